// Round 5
// baseline (189.981 us; speedup 1.0000x reference)
//
#include <hip/hip_runtime.h>

#define B_ 8
#define S_ 1024
#define E_ 768
#define H_ 12
#define D_ 64
#define HD_ 768
#define SCALE_ 0.125f

typedef short s16x8 __attribute__((ext_vector_type(8)));
typedef float f32x4 __attribute__((ext_vector_type(4)));
typedef unsigned short u16;
typedef unsigned int u32;

#define MFMA16(a,b,c) __builtin_amdgcn_mfma_f32_16x16x32_bf16((a),(b),(c),0,0,0)

__device__ __forceinline__ u16 f2bf(float x){
  unsigned u = __float_as_uint(x);
  u += 0x7fffu + ((u >> 16) & 1u);
  return (u16)(u >> 16);
}

__device__ __forceinline__ u32 pack2(float a, float b){
  return (u32)f2bf(a) | ((u32)f2bf(b) << 16);
}

__device__ __forceinline__ s16x8 cvt8(float4 a, float4 b){
  s16x8 r;
  r[0]=(short)f2bf(a.x); r[1]=(short)f2bf(a.y); r[2]=(short)f2bf(a.z); r[3]=(short)f2bf(a.w);
  r[4]=(short)f2bf(b.x); r[5]=(short)f2bf(b.y); r[6]=(short)f2bf(b.z); r[7]=(short)f2bf(b.w);
  return r;
}

#define GLOAD_LDS16(srcp, dstp)                                                        \
  __builtin_amdgcn_global_load_lds(                                                    \
      (const __attribute__((address_space(1))) u32*)(srcp),                            \
      (__attribute__((address_space(3))) u32*)(dstp), 16, 0, 0)

// ---------------------------------------------------------------------------
// Input conversion: q/k/v fp32 [B,S,E] -> Xbf bf16 [z][m][e], 8 elems/thread.
// ---------------------------------------------------------------------------
__global__ void convert_inputs(const float* __restrict__ qin, const float* __restrict__ kin,
                               const float* __restrict__ vin, u16* __restrict__ Xbf) {
  const int PER_Z = B_ * S_ * E_ / 8;       // 786432
  const int NV = 3 * PER_Z;
  for (int i = blockIdx.x * blockDim.x + threadIdx.x; i < NV; i += gridDim.x * blockDim.x) {
    int z = i / PER_Z;
    int r = i - z * PER_Z;
    const float* src = (z == 0) ? qin : ((z == 1) ? kin : vin);
    float4 f0 = *(const float4*)(src + (size_t)r * 8);
    float4 f1 = *(const float4*)(src + (size_t)r * 8 + 4);
    *(s16x8*)(Xbf + (size_t)i * 8) = cvt8(f0, f1);
  }
}

// ---------------------------------------------------------------------------
// Weight prep (coalesced, LDS 64x65 transpose tiles):
//   blocks 0..431 : Wq/Wk/Wv [H,E,D] -> Wt_qkv[z][n=h*64+d][e]
//   blocks 432..575: Wo [HD,E] -> Wot[n][k]
// ---------------------------------------------------------------------------
__global__ void prep_weights(const float* __restrict__ Wq, const float* __restrict__ Wk,
                             const float* __restrict__ Wv, const float* __restrict__ Wo,
                             u16* __restrict__ Wt_qkv, u16* __restrict__ Wot) {
  __shared__ float t[64][65];
  const int bid = blockIdx.x;
  const int tid = threadIdx.x;
  const int c = tid & 63;
  const int rg = tid >> 6;
  if (bid < 432) {
    int z = bid / 144, r = bid % 144, h = r / 12, et = r % 12;
    const float* W = (z == 0) ? Wq : ((z == 1) ? Wk : Wv);
    const float* src = W + (size_t)(h * E_ + et * 64) * D_;
#pragma unroll
    for (int p = 0; p < 16; ++p)
      t[rg + 4 * p][c] = src[(rg + 4 * p) * D_ + c];
    __syncthreads();
    u16* dst = Wt_qkv + (size_t)z * HD_ * E_ + (h * 64) * E_ + et * 64;
#pragma unroll
    for (int p = 0; p < 16; ++p) {
      int d = rg + 4 * p;
      dst[d * E_ + c] = f2bf(t[c][d]);
    }
  } else {
    int r = bid - 432; int kt = r / 12, nt = r % 12;
    const float* src = Wo + (size_t)(kt * 64) * E_ + nt * 64;
#pragma unroll
    for (int p = 0; p < 16; ++p)
      t[rg + 4 * p][c] = src[(rg + 4 * p) * E_ + c];
    __syncthreads();
    u16* dst = Wot + (size_t)(nt * 64) * HD_ + kt * 64;
#pragma unroll
    for (int p = 0; p < 16; ++p) {
      int nl = rg + 4 * p;
      dst[nl * HD_ + c] = f2bf(t[c][nl]);
    }
  }
}

// ---------------------------------------------------------------------------
// QKV projection GEMM v5: BM=256 x BN=128, BK=64, 8 waves (4M x 2N, 64x64 each).
// Counted-vmcnt pipeline: raw s_barrier, stage(t+2) issued after the barrier
// closing reads of buf[t&1], vmcnt(6) waits tile t+1 only (t+2's 6 loads
// per thread stay in flight across both barriers). LDS 96KB, 1 block/CU.
// ---------------------------------------------------------------------------
__launch_bounds__(512, 2)
__global__ void qkv_gemm(const u16* __restrict__ Xbf, const u16* __restrict__ Wt_qkv,
                         const float* __restrict__ bq, const float* __restrict__ bk,
                         const float* __restrict__ bv, u16* __restrict__ Qbf,
                         u16* __restrict__ Kbf, u16* __restrict__ Vt) {
  __shared__ __align__(16) u16 As[2][256 * 64];   // 64 KB
  __shared__ __align__(16) u16 Bs[2][128 * 64];   // 32 KB
  const int tid = threadIdx.x;
  const int lane = tid & 63;
  const int w = tid >> 6;          // 0..7
  const int wm = w >> 1;           // 0..3 (M)
  const int wn = w & 1;            // 0..1 (N)
  // bijective XCD chunking: 576 = 8 * 72; consecutive ids share (z, n-panel)
  const int lin = blockIdx.x;
  const int id = (lin & 7) * 72 + (lin >> 3);
  const int bz = id / 192;
  const int rem = id - bz * 192;
  const int m0 = (rem & 31) * 256;
  const int n0 = (rem >> 5) * 128;
  const u16* A  = Xbf + (size_t)bz * (B_ * S_ * E_);
  const u16* Wt = Wt_qkv + bz * (HD_ * E_);
  const float* bias = (bz == 0) ? bq : ((bz == 1) ? bk : bv);

  f32x4 acc[4][4];
#pragma unroll
  for (int i = 0; i < 4; ++i)
#pragma unroll
    for (int j = 0; j < 4; ++j) acc[i][j] = (f32x4){0.f, 0.f, 0.f, 0.f};

  const int g = lane >> 4;
  const int l15 = lane & 15;
  const int srow = lane >> 3;                 // row offset within 8-row slab
  const int sch  = (lane & 7) ^ srow;         // pre-swizzled 16B chunk

  // 6 global_load_lds per thread per K-tile (A: 4, B: 2)
#define QSTAGE(kt, bsel)                                                              \
  {                                                                                   \
    _Pragma("unroll")                                                                 \
    for (int i = 0; i < 4; ++i) {                                                     \
      int row = i * 64 + w * 8 + srow;                                                \
      GLOAD_LDS16(A + (size_t)(m0 + row) * E_ + (kt) * 64 + sch * 8,                  \
                  &As[bsel][(i * 64 + w * 8) * 64]);                                  \
    }                                                                                 \
    _Pragma("unroll")                                                                 \
    for (int j = 0; j < 2; ++j) {                                                     \
      int row = j * 64 + w * 8 + srow;                                                \
      GLOAD_LDS16(Wt + (n0 + row) * E_ + (kt) * 64 + sch * 8,                         \
                  &Bs[bsel][(j * 64 + w * 8) * 64]);                                  \
    }                                                                                 \
  }

  QSTAGE(0, 0);
  QSTAGE(1, 1);
  asm volatile("s_waitcnt vmcnt(6)" ::: "memory");   // tile 0 landed, tile 1 in flight
  __builtin_amdgcn_sched_barrier(0);
  __builtin_amdgcn_s_barrier();
  int cur = 0;
  for (int t = 0; t < 12; ++t) {
    const u16* Al = As[cur];
    const u16* Bl = Bs[cur];
#pragma unroll
    for (int kk = 0; kk < 2; ++kk) {
      const int kc = kk * 4 + g;
      s16x8 af[4], bfr[4];
#pragma unroll
      for (int i = 0; i < 4; ++i) {
        int row = wm * 64 + i * 16 + l15;
        af[i] = *(const s16x8*)(Al + row * 64 + ((kc ^ (row & 7)) << 3));
      }
#pragma unroll
      for (int j = 0; j < 4; ++j) {
        int row = wn * 64 + j * 16 + l15;
        bfr[j] = *(const s16x8*)(Bl + row * 64 + ((kc ^ (row & 7)) << 3));
      }
      __builtin_amdgcn_s_setprio(1);
#pragma unroll
      for (int i = 0; i < 4; ++i)
#pragma unroll
        for (int j = 0; j < 4; ++j) acc[i][j] = MFMA16(af[i], bfr[j], acc[i][j]);
      __builtin_amdgcn_s_setprio(0);
    }
    if (t < 11) {
      __builtin_amdgcn_s_barrier();              // all waves done reading buf[cur]
      if (t < 10) {
        QSTAGE(t + 2, cur);                      // refill just-freed buffer
        asm volatile("s_waitcnt vmcnt(6)" ::: "memory");  // t+1 landed; t+2 in flight
      } else {
        asm volatile("s_waitcnt vmcnt(0)" ::: "memory");  // last tile landed
      }
      __builtin_amdgcn_sched_barrier(0);
      __builtin_amdgcn_s_barrier();              // publish buf[cur^1]
      cur ^= 1;
    }
  }
#undef QSTAGE
  // epilogue: C/D map col=lane&15, row=(lane>>4)*4+r  [m89]
#pragma unroll
  for (int j = 0; j < 4; ++j) {
    int ng = n0 + wn * 64 + j * 16 + l15;
    float bvv = bias[ng];
    int h = ng >> 6, d = ng & 63;
#pragma unroll
    for (int i = 0; i < 4; ++i) {
#pragma unroll
      for (int r = 0; r < 4; ++r) {
        int m = m0 + wm * 64 + i * 16 + g * 4 + r;
        float v = acc[i][j][r] + bvv;
        int bb = m >> 10, s = m & 1023;
        if (bz == 0) {
          v *= SCALE_;
          Qbf[((bb * H_ + h) * S_ + s) * D_ + d] = f2bf(v);
        } else if (bz == 1) {
          Kbf[((bb * H_ + h) * S_ + s) * D_ + d] = f2bf(v);
        } else {
          Vt[((bb * H_ + h) * D_ + d) * S_ + s] = f2bf(v);
        }
      }
    }
  }
}

// ---------------------------------------------------------------------------
// Causal flash attention (unchanged).
// ---------------------------------------------------------------------------
__launch_bounds__(256)
__global__ void attn_kernel(const u16* __restrict__ Qbf, const u16* __restrict__ Kbf,
                            const u16* __restrict__ Vt, u16* __restrict__ concat) {
  __shared__ __align__(16) u16 Ks[2][64 * 64];
  __shared__ __align__(16) u16 Vs[2][64 * 64];
  __shared__ __align__(16) u16 Ps[4][2][16 * 64];
  const int tid = threadIdx.x;
  const int lane = tid & 63;
  const int w = tid >> 6;
  const int l15 = lane & 15;
  const int g = lane >> 4;
  const int qb = blockIdx.x & 7;
  const int bh = blockIdx.x >> 3;
  const int h = bh % H_;
  const int b = bh / H_;
  const u16* Qb = Qbf + (b * H_ + h) * S_ * D_;
  const u16* Kb = Kbf + (b * H_ + h) * S_ * D_;
  const u16* Vb = Vt  + (b * H_ + h) * D_ * S_;
  const int q0 = qb * 128;
  const int qrow_base = q0 + w * 32;

  s16x8 qf[2][2];
#pragma unroll
  for (int qg = 0; qg < 2; ++qg)
#pragma unroll
    for (int kk = 0; kk < 2; ++kk)
      qf[qg][kk] = *(const s16x8*)(Qb + (qrow_base + qg * 16 + l15) * D_ + kk * 32 + g * 8);

  f32x4 o[2][4];
#pragma unroll
  for (int qg = 0; qg < 2; ++qg)
#pragma unroll
    for (int dc = 0; dc < 4; ++dc) o[qg][dc] = (f32x4){0.f, 0.f, 0.f, 0.f};
  float lsum[2] = {0.f, 0.f};

  const int nt = 2 * qb + 2;
  const int srow = lane >> 3;
  const int schunk = lane & 7;

#define STAGE(tt, bsel)                                                              \
  {                                                                                  \
    const int t0s = (tt) * 64;                                                       \
    _Pragma("unroll")                                                                \
    for (int j = 0; j < 2; ++j) {                                                    \
      int row = w * 16 + j * 8 + srow;                                               \
      GLOAD_LDS16(Kb + (t0s + row) * D_ + ((schunk ^ (row & 7)) << 3),               \
                  &Ks[bsel][(w * 16 + j * 8) * 64]);                                 \
      GLOAD_LDS16(Vb + row * S_ + t0s + ((schunk ^ (row & 7)) << 3),                 \
                  &Vs[bsel][(w * 16 + j * 8) * 64]);                                 \
    }                                                                                \
  }

  STAGE(0, 0);
  __syncthreads();
  int cur = 0;
  for (int t = 0; t < nt; ++t) {
    if (t + 1 < nt) STAGE(t + 1, cur ^ 1);
    const int t0 = t * 64;
    const u16* Kl = Ks[cur];
    const u16* Vl = Vs[cur];
    f32x4 st[2][4];
#pragma unroll
    for (int qg = 0; qg < 2; ++qg)
#pragma unroll
      for (int c = 0; c < 4; ++c) st[qg][c] = (f32x4){0.f, 0.f, 0.f, 0.f};
#pragma unroll
    for (int kk = 0; kk < 2; ++kk) {
      s16x8 kf[4];
#pragma unroll
      for (int c = 0; c < 4; ++c) {
        int row = 16 * c + l15;
        kf[c] = *(const s16x8*)(Kl + row * 64 + ((((kk << 2) + g) ^ (row & 7)) << 3));
      }
#pragma unroll
      for (int qg = 0; qg < 2; ++qg)
#pragma unroll
        for (int c = 0; c < 4; ++c) st[qg][c] = MFMA16(kf[c], qf[qg][kk], st[qg][c]);
    }
#pragma unroll
    for (int qg = 0; qg < 2; ++qg) {
      const int qmin = qrow_base + qg * 16;
      if (t0 > qmin + 15) continue;
      const bool needmask = (t0 + 63 > qmin);
      const int qv = qmin + l15;
      u16* Pq = Ps[w][qg];
      float lacc = 0.f;
#pragma unroll
      for (int c = 0; c < 4; ++c) {
        float p[4];
#pragma unroll
        for (int r = 0; r < 4; ++r) {
          float s = st[qg][c][r];
          if (needmask && (t0 + 16 * c + 4 * g + r > qv)) s = -1e30f;
          p[r] = __expf(s);
          lacc += p[r];
        }
        int chunk = (2 * c + (g >> 1)) ^ (l15 & 7);
        *(uint2*)(Pq + l15 * 64 + (chunk << 3) + ((g & 1) << 2)) =
            make_uint2(pack2(p[0], p[1]), pack2(p[2], p[3]));
      }
      lsum[qg] += lacc;
    }
    asm volatile("s_waitcnt lgkmcnt(0)" ::: "memory");
    __builtin_amdgcn_sched_barrier(0);
#pragma unroll
    for (int kk = 0; kk < 2; ++kk) {
      s16x8 vf[4];
#pragma unroll
      for (int dc = 0; dc < 4; ++dc) {
        int row = 16 * dc + l15;
        vf[dc] = *(const s16x8*)(Vl + row * 64 + ((((kk << 2) + g) ^ (row & 7)) << 3));
      }
#pragma unroll
      for (int qg = 0; qg < 2; ++qg) {
        if (t0 > qrow_base + qg * 16 + 15) continue;
        s16x8 pf = *(const s16x8*)(Ps[w][qg] + l15 * 64 +
                                   ((((kk << 2) + g) ^ (l15 & 7)) << 3));
#pragma unroll
        for (int dc = 0; dc < 4; ++dc) o[qg][dc] = MFMA16(vf[dc], pf, o[qg][dc]);
      }
    }
    __syncthreads();
    cur ^= 1;
  }
#pragma unroll
  for (int qg = 0; qg < 2; ++qg) {
    float l = lsum[qg];
    l += __shfl_xor(l, 16);
    l += __shfl_xor(l, 32);
    float linv = 1.0f / l;
    int q = qrow_base + qg * 16 + l15;
    u16* Cr = concat + (b * S_ + q) * HD_ + h * D_;
#pragma unroll
    for (int dc = 0; dc < 4; ++dc) {
      *(uint2*)(Cr + dc * 16 + g * 4) =
          make_uint2(pack2(o[qg][dc][0] * linv, o[qg][dc][1] * linv),
                     pack2(o[qg][dc][2] * linv, o[qg][dc][3] * linv));
    }
  }
#undef STAGE
}

// ---------------------------------------------------------------------------
// Output projection v5: same counted-vmcnt structure as qkv_gemm. fp32 out.
// ---------------------------------------------------------------------------
__launch_bounds__(512, 2)
__global__ void out_gemm(const u16* __restrict__ concat, const u16* __restrict__ Wot,
                         const float* __restrict__ bo, float* __restrict__ out) {
  __shared__ __align__(16) u16 As[2][256 * 64];
  __shared__ __align__(16) u16 Bs[2][128 * 64];
  const int tid = threadIdx.x;
  const int lane = tid & 63;
  const int w = tid >> 6;
  const int wm = w >> 1;
  const int wn = w & 1;
  const int lin = blockIdx.x;
  const int id = (lin & 7) * 24 + (lin >> 3);    // 192 = 8*24, bijective
  const int m0 = (id & 31) * 256;
  const int n0 = (id >> 5) * 128;
  f32x4 acc[4][4];
#pragma unroll
  for (int i = 0; i < 4; ++i)
#pragma unroll
    for (int j = 0; j < 4; ++j) acc[i][j] = (f32x4){0.f, 0.f, 0.f, 0.f};
  const int g = lane >> 4;
  const int l15 = lane & 15;
  const int srow = lane >> 3;
  const int sch  = (lane & 7) ^ srow;

#define OSTAGE(kt, bsel)                                                              \
  {                                                                                   \
    _Pragma("unroll")                                                                 \
    for (int i = 0; i < 4; ++i) {                                                     \
      int row = i * 64 + w * 8 + srow;                                                \
      GLOAD_LDS16(concat + (size_t)(m0 + row) * HD_ + (kt) * 64 + sch * 8,            \
                  &As[bsel][(i * 64 + w * 8) * 64]);                                  \
    }                                                                                 \
    _Pragma("unroll")                                                                 \
    for (int j = 0; j < 2; ++j) {                                                     \
      int row = j * 64 + w * 8 + srow;                                                \
      GLOAD_LDS16(Wot + (n0 + row) * HD_ + (kt) * 64 + sch * 8,                       \
                  &Bs[bsel][(j * 64 + w * 8) * 64]);                                  \
    }                                                                                 \
  }

  OSTAGE(0, 0);
  OSTAGE(1, 1);
  asm volatile("s_waitcnt vmcnt(6)" ::: "memory");
  __builtin_amdgcn_sched_barrier(0);
  __builtin_amdgcn_s_barrier();
  int cur = 0;
  for (int t = 0; t < 12; ++t) {
    const u16* Al = As[cur];
    const u16* Bl = Bs[cur];
#pragma unroll
    for (int kk = 0; kk < 2; ++kk) {
      const int kc = kk * 4 + g;
      s16x8 af[4], bfr[4];
#pragma unroll
      for (int i = 0; i < 4; ++i) {
        int row = wm * 64 + i * 16 + l15;
        af[i] = *(const s16x8*)(Al + row * 64 + ((kc ^ (row & 7)) << 3));
      }
#pragma unroll
      for (int j = 0; j < 4; ++j) {
        int row = wn * 64 + j * 16 + l15;
        bfr[j] = *(const s16x8*)(Bl + row * 64 + ((kc ^ (row & 7)) << 3));
      }
      __builtin_amdgcn_s_setprio(1);
#pragma unroll
      for (int i = 0; i < 4; ++i)
#pragma unroll
        for (int j = 0; j < 4; ++j) acc[i][j] = MFMA16(af[i], bfr[j], acc[i][j]);
      __builtin_amdgcn_s_setprio(0);
    }
    if (t < 11) {
      __builtin_amdgcn_s_barrier();
      if (t < 10) {
        OSTAGE(t + 2, cur);
        asm volatile("s_waitcnt vmcnt(6)" ::: "memory");
      } else {
        asm volatile("s_waitcnt vmcnt(0)" ::: "memory");
      }
      __builtin_amdgcn_sched_barrier(0);
      __builtin_amdgcn_s_barrier();
      cur ^= 1;
    }
  }
#undef OSTAGE
#pragma unroll
  for (int j = 0; j < 4; ++j) {
    int ng = n0 + wn * 64 + j * 16 + l15;
    float bvv = bo[ng];
#pragma unroll
    for (int i = 0; i < 4; ++i) {
      int mrow = m0 + wm * 64 + i * 16 + g * 4;
#pragma unroll
      for (int r = 0; r < 4; ++r) out[(mrow + r) * E_ + ng] = acc[i][j][r] + bvv;
    }
  }
}

extern "C" void kernel_launch(void* const* d_in, const int* in_sizes, int n_in,
                              void* d_out, int out_size, void* d_ws, size_t ws_size,
                              hipStream_t stream) {
  const float* queries = (const float*)d_in[0];
  const float* keys    = (const float*)d_in[1];
  const float* values  = (const float*)d_in[2];
  // d_in[3] = attn_mask (causal tril; handled analytically)
  const float* Wq = (const float*)d_in[4];
  const float* bq = (const float*)d_in[5];
  const float* Wk = (const float*)d_in[6];
  const float* bk = (const float*)d_in[7];
  const float* Wv = (const float*)d_in[8];
  const float* bv = (const float*)d_in[9];
  const float* Wo = (const float*)d_in[10];
  const float* bo = (const float*)d_in[11];
  float* out = (float*)d_out;

  u16* Wt_qkv = (u16*)d_ws;                   // 3*768*768
  u16* Wot    = Wt_qkv + 3 * HD_ * E_;        // 768*768
  u16* Qbf    = Wot + E_ * HD_;               // B*H*S*D
  u16* Kbf    = Qbf + B_ * H_ * S_ * D_;
  u16* Vt     = Kbf + B_ * H_ * S_ * D_;
  // union region: Xbf (3*B*S*E, live convert->qkv) overlays concat (B*S*HD,
  // live attn->out). Temporally disjoint within each call; stream-ordered.
  u16* Xbf    = Vt + B_ * H_ * S_ * D_;
  u16* concat = Xbf;

  prep_weights<<<dim3(576), dim3(256), 0, stream>>>(Wq, Wk, Wv, Wo, Wt_qkv, Wot);
  convert_inputs<<<dim3(2048), dim3(256), 0, stream>>>(queries, keys, values, Xbf);
  qkv_gemm<<<dim3(576), dim3(512), 0, stream>>>(
      Xbf, Wt_qkv, bq, bk, bv, Qbf, Kbf, Vt);
  attn_kernel<<<dim3(768), dim3(256), 0, stream>>>(Qbf, Kbf, Vt, concat);
  out_gemm<<<dim3(192), dim3(512), 0, stream>>>(concat, Wot, bo, out);
}

// Round 6
// 147.775 us; speedup vs baseline: 1.2856x; 1.2856x over previous
//
#include <hip/hip_runtime.h>

#define B_ 8
#define S_ 1024
#define E_ 768
#define H_ 12
#define D_ 64
#define HD_ 768
#define SCALE_ 0.125f

typedef short s16x8 __attribute__((ext_vector_type(8)));
typedef float f32x4 __attribute__((ext_vector_type(4)));
typedef unsigned int u32x4 __attribute__((ext_vector_type(4)));
typedef unsigned short u16;
typedef unsigned int u32;

#define MFMA16(a,b,c) __builtin_amdgcn_mfma_f32_16x16x32_bf16((a),(b),(c),0,0,0)

__device__ __forceinline__ u16 f2bf(float x){
  unsigned u = __float_as_uint(x);
  u += 0x7fffu + ((u >> 16) & 1u);
  return (u16)(u >> 16);
}

__device__ __forceinline__ u32 pack2(float a, float b){
  return (u32)f2bf(a) | ((u32)f2bf(b) << 16);
}

// HW packed f32->bf16 (RNE). No builtin on gfx950 (m240) -> inline asm.
__device__ __forceinline__ u32 cvtpk(float a, float b){
  u32 r;
  asm("v_cvt_pk_bf16_f32 %0, %1, %2" : "=v"(r) : "v"(a), "v"(b));
  return r;
}

#define GLOAD_LDS16(srcp, dstp)                                                        \
  __builtin_amdgcn_global_load_lds(                                                    \
      (const __attribute__((address_space(1))) u32*)(srcp),                            \
      (__attribute__((address_space(3))) u32*)(dstp), 16, 0, 0)

// ---------------------------------------------------------------------------
// Weight prep (coalesced, LDS 64x65 transpose tiles):
//   blocks 0..431 : Wq/Wk/Wv [H,E,D] -> Wt_qkv[z][n=h*64+d][e]
//   blocks 432..575: Wo [HD,E] -> Wot[n][k]
// ---------------------------------------------------------------------------
__global__ void prep_weights(const float* __restrict__ Wq, const float* __restrict__ Wk,
                             const float* __restrict__ Wv, const float* __restrict__ Wo,
                             u16* __restrict__ Wt_qkv, u16* __restrict__ Wot) {
  __shared__ float t[64][65];
  const int bid = blockIdx.x;
  const int tid = threadIdx.x;
  const int c = tid & 63;
  const int rg = tid >> 6;
  if (bid < 432) {
    int z = bid / 144, r = bid % 144, h = r / 12, et = r % 12;
    const float* W = (z == 0) ? Wq : ((z == 1) ? Wk : Wv);
    const float* src = W + (size_t)(h * E_ + et * 64) * D_;
#pragma unroll
    for (int p = 0; p < 16; ++p)
      t[rg + 4 * p][c] = src[(rg + 4 * p) * D_ + c];
    __syncthreads();
    u16* dst = Wt_qkv + (size_t)z * HD_ * E_ + (h * 64) * E_ + et * 64;
#pragma unroll
    for (int p = 0; p < 16; ++p) {
      int d = rg + 4 * p;
      dst[d * E_ + c] = f2bf(t[c][d]);
    }
  } else {
    int r = bid - 432; int kt = r / 12, nt = r % 12;
    const float* src = Wo + (size_t)(kt * 64) * E_ + nt * 64;
#pragma unroll
    for (int p = 0; p < 16; ++p)
      t[rg + 4 * p][c] = src[(rg + 4 * p) * E_ + c];
    __syncthreads();
    u16* dst = Wot + (size_t)(nt * 64) * HD_ + kt * 64;
#pragma unroll
    for (int p = 0; p < 16; ++p) {
      int nl = rg + 4 * p;
      dst[nl * HD_ + c] = f2bf(t[c][nl]);
    }
  }
}

// ---------------------------------------------------------------------------
// QKV projection GEMM v6: fused fp32-A path. Single-buffer 2-barrier m97
// structure (proven 72us at this shape). A staged as FP32 straight from the
// original inputs via global_load_lds (16-chunk XOR pre-swizzle, 32KB tile);
// f32->bf16 conversion happens in-register (v_cvt_pk_bf16_f32) during
// fragment assembly. B bf16 from prepped weights (8-chunk swizzle, 16KB).
// No convert_inputs pass, no Xbf round-trip.
// z==0 -> Qbf [B,H,S,D] (pre-scaled); z==1 -> Kbf; z==2 -> Vt [B,H,D,S].
// ---------------------------------------------------------------------------
__launch_bounds__(256)
__global__ void qkv_gemm(const float* __restrict__ qin, const float* __restrict__ kin,
                         const float* __restrict__ vin, const u16* __restrict__ Wt_qkv,
                         const float* __restrict__ bq, const float* __restrict__ bk,
                         const float* __restrict__ bv, u16* __restrict__ Qbf,
                         u16* __restrict__ Kbf, u16* __restrict__ Vt) {
  __shared__ __align__(16) float Asf[128 * 64];   // 32 KB fp32 A tile
  __shared__ __align__(16) u16  Bs[128 * 64];     // 16 KB bf16 B tile
  const int tid = threadIdx.x;
  const int lane = tid & 63;
  const int w = tid >> 6;
  const int wr = w >> 1, wc = w & 1;
  const int m0 = blockIdx.x * 128;
  const int n0 = blockIdx.y * 128;
  const int z  = blockIdx.z;
  const float* in = (z == 0) ? qin : ((z == 1) ? kin : vin);
  const u16* Wt = Wt_qkv + z * (HD_ * E_);
  const float* bias = (z == 0) ? bq : ((z == 1) ? bk : bv);

  f32x4 acc[4][4];
#pragma unroll
  for (int i = 0; i < 4; ++i)
#pragma unroll
    for (int j = 0; j < 4; ++j) acc[i][j] = (f32x4){0.f, 0.f, 0.f, 0.f};

  const int g = lane >> 4;
  const int l15 = lane & 15;
  // A staging: wave covers 4 rows x 16 chunks (16B = 4 floats each)
  const int arow = lane >> 4;          // 0..3 within 4-row slab
  const int ach  = lane & 15;          // 16B chunk within 256B row
  // B staging: wave covers 8 rows x 8 chunks (16B = 8 bf16 each)
  const int brow = lane >> 3;          // 0..7
  const int bch  = lane & 7;

  for (int kt = 0; kt < E_ / 64; ++kt) {
    __syncthreads();
#pragma unroll
    for (int i = 0; i < 8; ++i) {       // A: 128 rows, 4 per wave-pass
      int row = i * 16 + w * 4 + arow;
      GLOAD_LDS16(in + (size_t)(m0 + row) * E_ + kt * 64 + ((ach ^ (row & 15)) << 2),
                  &Asf[(i * 16 + w * 4) * 64]);
    }
#pragma unroll
    for (int j = 0; j < 4; ++j) {       // B: 128 rows, 8 per wave-pass
      int row = j * 32 + w * 8 + brow;
      GLOAD_LDS16(Wt + (n0 + row) * E_ + kt * 64 + ((bch ^ (row & 7)) << 3),
                  &Bs[(j * 32 + w * 8) * 64]);
    }
    __syncthreads();
#pragma unroll
    for (int kk = 0; kk < 2; ++kk) {
      const int kc = kk * 4 + g;
      s16x8 af[4], bfr[4];
#pragma unroll
      for (int i = 0; i < 4; ++i) {
        int row = wr * 64 + i * 16 + l15;
        const float* rp = Asf + row * 64;
        f32x4 lo = *(const f32x4*)(rp + ((( 2 * kc )     ^ (row & 15)) << 2));
        f32x4 hi = *(const f32x4*)(rp + ((( 2 * kc + 1 ) ^ (row & 15)) << 2));
        u32x4 q;
        q[0] = cvtpk(lo[0], lo[1]);
        q[1] = cvtpk(lo[2], lo[3]);
        q[2] = cvtpk(hi[0], hi[1]);
        q[3] = cvtpk(hi[2], hi[3]);
        af[i] = __builtin_bit_cast(s16x8, q);
      }
#pragma unroll
      for (int j = 0; j < 4; ++j) {
        int row = wc * 64 + j * 16 + l15;
        bfr[j] = *(const s16x8*)(Bs + row * 64 + ((kc ^ (row & 7)) << 3));
      }
#pragma unroll
      for (int i = 0; i < 4; ++i)
#pragma unroll
        for (int j = 0; j < 4; ++j) acc[i][j] = MFMA16(af[i], bfr[j], acc[i][j]);
    }
  }
  // epilogue: C/D map col=lane&15, row=(lane>>4)*4+r  [m89]
#pragma unroll
  for (int j = 0; j < 4; ++j) {
    int ng = n0 + wc * 64 + j * 16 + l15;
    float bvv = bias[ng];
    int h = ng >> 6, d = ng & 63;
#pragma unroll
    for (int i = 0; i < 4; ++i) {
#pragma unroll
      for (int r = 0; r < 4; ++r) {
        int m = m0 + wr * 64 + i * 16 + g * 4 + r;
        float v = acc[i][j][r] + bvv;
        int bb = m >> 10, s = m & 1023;
        if (z == 0) {
          v *= SCALE_;
          Qbf[((bb * H_ + h) * S_ + s) * D_ + d] = f2bf(v);
        } else if (z == 1) {
          Kbf[((bb * H_ + h) * S_ + s) * D_ + d] = f2bf(v);
        } else {
          Vt[((bb * H_ + h) * D_ + d) * S_ + s] = f2bf(v);
        }
      }
    }
  }
}

// ---------------------------------------------------------------------------
// Causal flash attention (unchanged — proven).
// ---------------------------------------------------------------------------
__launch_bounds__(256)
__global__ void attn_kernel(const u16* __restrict__ Qbf, const u16* __restrict__ Kbf,
                            const u16* __restrict__ Vt, u16* __restrict__ concat) {
  __shared__ __align__(16) u16 Ks[2][64 * 64];
  __shared__ __align__(16) u16 Vs[2][64 * 64];
  __shared__ __align__(16) u16 Ps[4][2][16 * 64];
  const int tid = threadIdx.x;
  const int lane = tid & 63;
  const int w = tid >> 6;
  const int l15 = lane & 15;
  const int g = lane >> 4;
  const int qb = blockIdx.x & 7;
  const int bh = blockIdx.x >> 3;
  const int h = bh % H_;
  const int b = bh / H_;
  const u16* Qb = Qbf + (b * H_ + h) * S_ * D_;
  const u16* Kb = Kbf + (b * H_ + h) * S_ * D_;
  const u16* Vb = Vt  + (b * H_ + h) * D_ * S_;
  const int q0 = qb * 128;
  const int qrow_base = q0 + w * 32;

  s16x8 qf[2][2];
#pragma unroll
  for (int qg = 0; qg < 2; ++qg)
#pragma unroll
    for (int kk = 0; kk < 2; ++kk)
      qf[qg][kk] = *(const s16x8*)(Qb + (qrow_base + qg * 16 + l15) * D_ + kk * 32 + g * 8);

  f32x4 o[2][4];
#pragma unroll
  for (int qg = 0; qg < 2; ++qg)
#pragma unroll
    for (int dc = 0; dc < 4; ++dc) o[qg][dc] = (f32x4){0.f, 0.f, 0.f, 0.f};
  float lsum[2] = {0.f, 0.f};

  const int nt = 2 * qb + 2;
  const int srow = lane >> 3;
  const int schunk = lane & 7;

#define STAGE(tt, bsel)                                                              \
  {                                                                                  \
    const int t0s = (tt) * 64;                                                       \
    _Pragma("unroll")                                                                \
    for (int j = 0; j < 2; ++j) {                                                    \
      int row = w * 16 + j * 8 + srow;                                               \
      GLOAD_LDS16(Kb + (t0s + row) * D_ + ((schunk ^ (row & 7)) << 3),               \
                  &Ks[bsel][(w * 16 + j * 8) * 64]);                                 \
      GLOAD_LDS16(Vb + row * S_ + t0s + ((schunk ^ (row & 7)) << 3),                 \
                  &Vs[bsel][(w * 16 + j * 8) * 64]);                                 \
    }                                                                                \
  }

  STAGE(0, 0);
  __syncthreads();
  int cur = 0;
  for (int t = 0; t < nt; ++t) {
    if (t + 1 < nt) STAGE(t + 1, cur ^ 1);
    const int t0 = t * 64;
    const u16* Kl = Ks[cur];
    const u16* Vl = Vs[cur];
    f32x4 st[2][4];
#pragma unroll
    for (int qg = 0; qg < 2; ++qg)
#pragma unroll
      for (int c = 0; c < 4; ++c) st[qg][c] = (f32x4){0.f, 0.f, 0.f, 0.f};
#pragma unroll
    for (int kk = 0; kk < 2; ++kk) {
      s16x8 kf[4];
#pragma unroll
      for (int c = 0; c < 4; ++c) {
        int row = 16 * c + l15;
        kf[c] = *(const s16x8*)(Kl + row * 64 + ((((kk << 2) + g) ^ (row & 7)) << 3));
      }
#pragma unroll
      for (int qg = 0; qg < 2; ++qg)
#pragma unroll
        for (int c = 0; c < 4; ++c) st[qg][c] = MFMA16(kf[c], qf[qg][kk], st[qg][c]);
    }
#pragma unroll
    for (int qg = 0; qg < 2; ++qg) {
      const int qmin = qrow_base + qg * 16;
      if (t0 > qmin + 15) continue;
      const bool needmask = (t0 + 63 > qmin);
      const int qv = qmin + l15;
      u16* Pq = Ps[w][qg];
      float lacc = 0.f;
#pragma unroll
      for (int c = 0; c < 4; ++c) {
        float p[4];
#pragma unroll
        for (int r = 0; r < 4; ++r) {
          float s = st[qg][c][r];
          if (needmask && (t0 + 16 * c + 4 * g + r > qv)) s = -1e30f;
          p[r] = __expf(s);
          lacc += p[r];
        }
        int chunk = (2 * c + (g >> 1)) ^ (l15 & 7);
        *(uint2*)(Pq + l15 * 64 + (chunk << 3) + ((g & 1) << 2)) =
            make_uint2(pack2(p[0], p[1]), pack2(p[2], p[3]));
      }
      lsum[qg] += lacc;
    }
    asm volatile("s_waitcnt lgkmcnt(0)" ::: "memory");
    __builtin_amdgcn_sched_barrier(0);
#pragma unroll
    for (int kk = 0; kk < 2; ++kk) {
      s16x8 vf[4];
#pragma unroll
      for (int dc = 0; dc < 4; ++dc) {
        int row = 16 * dc + l15;
        vf[dc] = *(const s16x8*)(Vl + row * 64 + ((((kk << 2) + g) ^ (row & 7)) << 3));
      }
#pragma unroll
      for (int qg = 0; qg < 2; ++qg) {
        if (t0 > qrow_base + qg * 16 + 15) continue;
        s16x8 pf = *(const s16x8*)(Ps[w][qg] + l15 * 64 +
                                   ((((kk << 2) + g) ^ (l15 & 7)) << 3));
#pragma unroll
        for (int dc = 0; dc < 4; ++dc) o[qg][dc] = MFMA16(vf[dc], pf, o[qg][dc]);
      }
    }
    __syncthreads();
    cur ^= 1;
  }
#pragma unroll
  for (int qg = 0; qg < 2; ++qg) {
    float l = lsum[qg];
    l += __shfl_xor(l, 16);
    l += __shfl_xor(l, 32);
    float linv = 1.0f / l;
    int q = qrow_base + qg * 16 + l15;
    u16* Cr = concat + (b * S_ + q) * HD_ + h * D_;
#pragma unroll
    for (int dc = 0; dc < 4; ++dc) {
      *(uint2*)(Cr + dc * 16 + g * 4) =
          make_uint2(pack2(o[qg][dc][0] * linv, o[qg][dc][1] * linv),
                     pack2(o[qg][dc][2] * linv, o[qg][dc][3] * linv));
    }
  }
#undef STAGE
}

// ---------------------------------------------------------------------------
// Output projection (round-3 proven structure): single-buffer, 32KB, 2D grid.
// ---------------------------------------------------------------------------
__launch_bounds__(256)
__global__ void out_gemm(const u16* __restrict__ concat, const u16* __restrict__ Wot,
                         const float* __restrict__ bo, float* __restrict__ out) {
  __shared__ __align__(16) u16 As[128 * 64];
  __shared__ __align__(16) u16 Bs[128 * 64];
  const int tid = threadIdx.x;
  const int lane = tid & 63;
  const int w = tid >> 6;
  const int wr = w >> 1, wc = w & 1;
  const int m0 = blockIdx.x * 128;
  const int n0 = blockIdx.y * 128;
  f32x4 acc[4][4];
#pragma unroll
  for (int i = 0; i < 4; ++i)
#pragma unroll
    for (int j = 0; j < 4; ++j) acc[i][j] = (f32x4){0.f, 0.f, 0.f, 0.f};
  const int g = lane >> 4;
  const int l15 = lane & 15;
  const int srow = lane >> 3;
  const int sch  = (lane & 7) ^ srow;

  for (int kt = 0; kt < HD_ / 64; ++kt) {
    __syncthreads();
#pragma unroll
    for (int i = 0; i < 4; ++i) {
      int row = i * 32 + w * 8 + srow;
      GLOAD_LDS16(concat + (m0 + row) * HD_ + kt * 64 + sch * 8, &As[(i * 32 + w * 8) * 64]);
      GLOAD_LDS16(Wot    + (n0 + row) * HD_ + kt * 64 + sch * 8, &Bs[(i * 32 + w * 8) * 64]);
    }
    __syncthreads();
#pragma unroll
    for (int kk = 0; kk < 2; ++kk) {
      const int kc = kk * 4 + g;
      s16x8 af[4], bfr[4];
#pragma unroll
      for (int i = 0; i < 4; ++i) {
        int row = wr * 64 + i * 16 + l15;
        af[i] = *(const s16x8*)(As + row * 64 + ((kc ^ (row & 7)) << 3));
      }
#pragma unroll
      for (int j = 0; j < 4; ++j) {
        int row = wc * 64 + j * 16 + l15;
        bfr[j] = *(const s16x8*)(Bs + row * 64 + ((kc ^ (row & 7)) << 3));
      }
#pragma unroll
      for (int i = 0; i < 4; ++i)
#pragma unroll
        for (int j = 0; j < 4; ++j) acc[i][j] = MFMA16(af[i], bfr[j], acc[i][j]);
    }
  }
#pragma unroll
  for (int j = 0; j < 4; ++j) {
    int ng = n0 + wc * 64 + j * 16 + l15;
    float bvv = bo[ng];
#pragma unroll
    for (int i = 0; i < 4; ++i) {
      int mrow = m0 + wr * 64 + i * 16 + g * 4;
#pragma unroll
      for (int r = 0; r < 4; ++r) out[(mrow + r) * E_ + ng] = acc[i][j][r] + bvv;
    }
  }
}

extern "C" void kernel_launch(void* const* d_in, const int* in_sizes, int n_in,
                              void* d_out, int out_size, void* d_ws, size_t ws_size,
                              hipStream_t stream) {
  const float* queries = (const float*)d_in[0];
  const float* keys    = (const float*)d_in[1];
  const float* values  = (const float*)d_in[2];
  // d_in[3] = attn_mask (causal tril; handled analytically)
  const float* Wq = (const float*)d_in[4];
  const float* bq = (const float*)d_in[5];
  const float* Wk = (const float*)d_in[6];
  const float* bk = (const float*)d_in[7];
  const float* Wv = (const float*)d_in[8];
  const float* bv = (const float*)d_in[9];
  const float* Wo = (const float*)d_in[10];
  const float* bo = (const float*)d_in[11];
  float* out = (float*)d_out;

  u16* Wt_qkv = (u16*)d_ws;                   // 3*768*768
  u16* Wot    = Wt_qkv + 3 * HD_ * E_;        // 768*768
  u16* Qbf    = Wot + E_ * HD_;               // B*H*S*D
  u16* Kbf    = Qbf + B_ * H_ * S_ * D_;
  u16* Vt     = Kbf + B_ * H_ * S_ * D_;
  u16* concat = Vt  + B_ * H_ * S_ * D_;      // B*S*HD

  prep_weights<<<dim3(576), dim3(256), 0, stream>>>(Wq, Wk, Wv, Wo, Wt_qkv, Wot);
  qkv_gemm<<<dim3(64, 6, 3), dim3(256), 0, stream>>>(
      queries, keys, values, Wt_qkv, bq, bk, bv, Qbf, Kbf, Vt);
  attn_kernel<<<dim3(768), dim3(256), 0, stream>>>(Qbf, Kbf, Vt, concat);
  out_gemm<<<dim3(64, 6), dim3(256), 0, stream>>>(concat, Wot, bo, out);
}